// Round 6
// baseline (334.724 us; speedup 1.0000x reference)
//
#include <hip/hip_runtime.h>
#include <math.h>

#define N_NODES 100000
#define N_EDGES 1600000
#define F_IN 165
#define KPAD 192
#define NEG 0.2f
#define NB 98            // ceil(N_NODES / 1024) scan blocks
#define NXCD 8
#define RSZ 12500        // N_NODES / NXCD, exact
#define EPB 1024         // edges per block-chunk (256 thr x 4)
#define NCHUNK ((N_EDGES + EPB - 1) / EPB)

typedef __attribute__((ext_vector_type(8))) short short8v;
typedef __attribute__((ext_vector_type(4))) float f32x4;

static __device__ __forceinline__ unsigned short f2bf(float f) {
    unsigned int u = __float_as_uint(f);
    unsigned int r = (u + 0x7FFFu + ((u >> 16) & 1u)) >> 16;
    return (unsigned short)r;
}
static __device__ __forceinline__ float bf2f(unsigned short b) {
    return __uint_as_float((unsigned int)b << 16);
}

// ---------------- W1 -> transposed bf16 hi/lo [64 cols][192 k] ----------------
__global__ __launch_bounds__(256) void k_wconv(const float* __restrict__ W1,
                                               unsigned short* __restrict__ Wth,
                                               unsigned short* __restrict__ Wtl) {
    int i = blockIdx.x * 256 + threadIdx.x;
    if (i >= 64 * KPAD) return;
    int col = i / KPAD, k = i % KPAD;
    float f = (k < F_IN) ? W1[k * 64 + col] : 0.f;
    unsigned short hi = f2bf(f);
    Wth[i] = hi;
    Wtl[i] = f2bf(f - bf2f(hi));
}

// ---------------- x -> bf16 hi/lo, row-major [N][192] (k padded) ----------------
// one short8 output vector per thread; coalesced writes, coalesced-ish reads.
__global__ __launch_bounds__(256) void k_xconv(const float* __restrict__ x,
                                               unsigned short* __restrict__ xh,
                                               unsigned short* __restrict__ xl) {
    int v = blockIdx.x * 256 + threadIdx.x;      // vector index; 24 per row
    if (v >= N_NODES * 24) return;
    int row = v / 24, kk = (v - row * 24) * 8;
    const float* xp = x + row * F_IN + kk;
    short8v h, l;
    #pragma unroll
    for (int j = 0; j < 8; ++j) {
        float f = (kk + j < F_IN) ? xp[j] : 0.f;
        unsigned short hi = f2bf(f);
        h[j] = (short)hi;
        l[j] = (short)f2bf(f - bf2f(hi));
    }
    *(short8v*)(xh + (size_t)v * 8) = h;
    *(short8v*)(xl + (size_t)v * 8) = l;
}

// ---------------- K1: h1 = x @ W1 via bf16 MFMA, register-direct, no LDS ----------------
// 4 waves/block, each wave = 16 rows x 64 cols. No barriers.
// A-frag: lane l holds x[row = rowblk*16 + (l&15)][k = k0 + (l>>4)*8 + j]
// C/D: col = l&15 (+16*ct), row = (l>>4)*4 + reg.
__global__ __launch_bounds__(256) void k_gemm1(const unsigned short* __restrict__ xh,
                                               const unsigned short* __restrict__ xl,
                                               const unsigned short* __restrict__ Wth,
                                               const unsigned short* __restrict__ Wtl,
                                               const float* __restrict__ a_src1,
                                               const float* __restrict__ a_dst1,
                                               float* __restrict__ h1,
                                               float* __restrict__ as1,
                                               float* __restrict__ ad1) {
    const int t = threadIdx.x;
    const int w = t >> 6, lane = t & 63;
    const int rowblk = blockIdx.x * 4 + w;       // 16-row group per wave
    if (rowblk * 16 >= N_NODES) return;          // N_NODES % 16 == 0
    const int lrow = lane & 15, lk = lane >> 4;
    const int arow = rowblk * 16 + lrow;

    const unsigned short* xhp = xh + (size_t)arow * KPAD + lk * 8;
    const unsigned short* xlp = xl + (size_t)arow * KPAD + lk * 8;

    f32x4 acc[4] = {};
    #pragma unroll
    for (int c = 0; c < 6; ++c) {
        short8v a_h = *(const short8v*)(xhp + c * 32);
        short8v a_l = *(const short8v*)(xlp + c * 32);
        #pragma unroll
        for (int ct = 0; ct < 4; ++ct) {
            const unsigned short* wb = Wth + (ct * 16 + lrow) * KPAD + c * 32 + lk * 8;
            const unsigned short* wl = Wtl + (ct * 16 + lrow) * KPAD + c * 32 + lk * 8;
            short8v b_h = *(const short8v*)wb;
            short8v b_l = *(const short8v*)wl;
            acc[ct] = __builtin_amdgcn_mfma_f32_16x16x32_bf16(a_h, b_h, acc[ct], 0, 0, 0);
            acc[ct] = __builtin_amdgcn_mfma_f32_16x16x32_bf16(a_h, b_l, acc[ct], 0, 0, 0);
            acc[ct] = __builtin_amdgcn_mfma_f32_16x16x32_bf16(a_l, b_h, acc[ct], 0, 0, 0);
        }
    }

    // epilogue: h1 store + fused per-head alpha reductions
    #pragma unroll
    for (int ct = 0; ct < 4; ++ct) {
        int colbase = ct * 16 + lrow;
        float av = a_src1[colbase], dv = a_dst1[colbase];
        #pragma unroll
        for (int r = 0; r < 4; ++r) {
            int row = rowblk * 16 + lk * 4 + r;
            float v = acc[ct][r];
            h1[row * 64 + colbase] = v;
            float ps = v * av, pd = v * dv;
            ps += __shfl_xor(ps, 1); ps += __shfl_xor(ps, 2); ps += __shfl_xor(ps, 4);
            pd += __shfl_xor(pd, 1); pd += __shfl_xor(pd, 2); pd += __shfl_xor(pd, 4);
            if ((lane & 7) == 0) {
                int head = ct * 2 + (lrow >> 3);
                as1[row * 8 + head] = ps;
                ad1[row * 8 + head] = pd;
            }
        }
    }
}

// ---------------- CSR build, XCD-range-partitioned ----------------
__global__ __launch_bounds__(256) void k_hist(const int* __restrict__ ei,
                                              int* __restrict__ deg) {
    int r = blockIdx.x & (NXCD - 1);
    int chunk = blockIdx.x >> 3;
    int lo = r * RSZ;
    long e0 = (long)chunk * EPB + threadIdx.x * 4;
    if (e0 >= N_EDGES) return;
    int4 d4 = *(const int4*)(ei + N_EDGES + e0);
    #pragma unroll
    for (int k = 0; k < 4; ++k) {
        int d = (&d4.x)[k];
        if ((unsigned)(d - lo) < RSZ) atomicAdd(&deg[d], 1);
    }
}

__global__ __launch_bounds__(256) void k_scan_a(const int* __restrict__ deg,
                                                int* __restrict__ S,
                                                int* __restrict__ blockSum) {
    __shared__ int lds[256];
    int t = threadIdx.x;
    int base = blockIdx.x * 1024 + t * 4;
    int v[4]; int sum = 0;
    #pragma unroll
    for (int k = 0; k < 4; ++k) { int i = base + k; v[k] = (i < N_NODES) ? deg[i] : 0; sum += v[k]; }
    lds[t] = sum; __syncthreads();
    for (int off = 1; off < 256; off <<= 1) {
        int x = lds[t];
        int y = (t >= off) ? lds[t - off] : 0;
        __syncthreads();
        lds[t] = x + y;
        __syncthreads();
    }
    int run = lds[t] - sum;
    #pragma unroll
    for (int k = 0; k < 4; ++k) {
        run += v[k];
        int i = base + k;
        if (i < N_NODES) S[i] = run;
    }
    if (t == 255) blockSum[blockIdx.x] = lds[255];
}

__global__ __launch_bounds__(256) void k_scan_b(const int* __restrict__ blockSum,
                                                int* __restrict__ blockOff) {
    __shared__ int lds[256];
    int t = threadIdx.x;
    int v = (t < NB) ? blockSum[t] : 0;
    lds[t] = v; __syncthreads();
    for (int off = 1; off < 256; off <<= 1) {
        int x = lds[t];
        int y = (t >= off) ? lds[t - off] : 0;
        __syncthreads();
        lds[t] = x + y;
        __syncthreads();
    }
    if (t < NB) blockOff[t] = lds[t] - v;
}

__global__ __launch_bounds__(256) void k_scan_c(int* __restrict__ S,
                                                const int* __restrict__ deg,
                                                const int* __restrict__ blockOff,
                                                int* __restrict__ cursor) {
    int i = blockIdx.x * 256 + threadIdx.x;
    if (i < N_NODES) {
        int s = S[i] + blockOff[i >> 10];
        S[i] = s;
        cursor[i] = s - deg[i];
    }
}

__global__ __launch_bounds__(256) void k_scatter(const int* __restrict__ ei,
                                                 int* __restrict__ cursor,
                                                 int* __restrict__ ssrc) {
    int r = blockIdx.x & (NXCD - 1);
    int chunk = blockIdx.x >> 3;
    int lo = r * RSZ;
    long e0 = (long)chunk * EPB + threadIdx.x * 4;
    if (e0 >= N_EDGES) return;
    int4 s4 = *(const int4*)(ei + e0);
    int4 d4 = *(const int4*)(ei + N_EDGES + e0);
    #pragma unroll
    for (int k = 0; k < 4; ++k) {
        int d = (&d4.x)[k];
        if ((unsigned)(d - lo) < RSZ) {
            int pos = atomicAdd(&cursor[d], 1);
            ssrc[pos] = (&s4.x)[k];
        }
    }
}

// ---------------- layer-1 aggregate + elu + @W2 + alpha2, fused ----------------
__global__ __launch_bounds__(256) void k_agg1(const int* __restrict__ ssrc,
                                              const int* __restrict__ S,
                                              const int* __restrict__ deg,
                                              const float* __restrict__ h1,
                                              const float* __restrict__ as1,
                                              const float* __restrict__ ad1,
                                              const float* __restrict__ b1,
                                              const float* __restrict__ W2,
                                              const float* __restrict__ a_src2,
                                              const float* __restrict__ a_dst2,
                                              float4* __restrict__ pk2) {
    int node = blockIdx.x * 4 + (threadIdx.x >> 6);
    int lane = threadIdx.x & 63;
    if (node >= N_NODES) return;
    int h = lane >> 3;
    int end = S[node], start = end - deg[node];
    float adh = ad1[node * 8 + h];
    float ev = as1[node * 8 + h] + adh;
    ev = fmaxf(ev, NEG * ev);
    float w = __expf(ev);
    float acc = w * h1[node * 64 + lane];
    float z = w;

    for (int c = start; c < end; c += 64) {
        int cnt = end - c; if (cnt > 64) cnt = 64;
        int sidx = (lane < cnt) ? ssrc[c + lane] : 0;
        int k = 0;
        for (; k + 4 <= cnt; k += 4) {
            int s0 = __shfl(sidx, k);
            int s1 = __shfl(sidx, k + 1);
            int s2 = __shfl(sidx, k + 2);
            int s3 = __shfl(sidx, k + 3);
            float a0 = as1[s0 * 8 + h];
            float a1 = as1[s1 * 8 + h];
            float a2 = as1[s2 * 8 + h];
            float a3 = as1[s3 * 8 + h];
            float g0 = h1[s0 * 64 + lane];
            float g1 = h1[s1 * 64 + lane];
            float g2 = h1[s2 * 64 + lane];
            float g3 = h1[s3 * 64 + lane];
            float e0 = a0 + adh; e0 = fmaxf(e0, NEG * e0); float w0 = __expf(e0);
            float e1 = a1 + adh; e1 = fmaxf(e1, NEG * e1); float w1 = __expf(e1);
            float e2 = a2 + adh; e2 = fmaxf(e2, NEG * e2); float w2 = __expf(e2);
            float e3 = a3 + adh; e3 = fmaxf(e3, NEG * e3); float w3 = __expf(e3);
            acc = fmaf(w0, g0, acc); acc = fmaf(w1, g1, acc);
            acc = fmaf(w2, g2, acc); acc = fmaf(w3, g3, acc);
            z += (w0 + w1) + (w2 + w3);
        }
        for (; k < cnt; ++k) {
            int s = __shfl(sidx, k);
            float a = as1[s * 8 + h];
            float g = h1[s * 64 + lane];
            float e2 = a + adh; e2 = fmaxf(e2, NEG * e2);
            float ww = __expf(e2);
            acc = fmaf(ww, g, acc);
            z += ww;
        }
    }

    float o = acc / z + b1[lane];
    o = o > 0.f ? o : expm1f(o);
    float p0 = o * W2[lane * 2 + 0];
    float p1 = o * W2[lane * 2 + 1];
    #pragma unroll
    for (int m = 1; m < 64; m <<= 1) { p0 += __shfl_xor(p0, m); p1 += __shfl_xor(p1, m); }
    if (lane == 0) {
        pk2[node] = make_float4(p0, p1,
                                p0 * a_src2[0] + p1 * a_src2[1],
                                p0 * a_dst2[0] + p1 * a_dst2[1]);
    }
}

// ---------------- layer-2 aggregate + log_softmax, fused ----------------
__global__ __launch_bounds__(256) void k_agg2(const int* __restrict__ ssrc,
                                              const int* __restrict__ S,
                                              const int* __restrict__ deg,
                                              const float4* __restrict__ pk2,
                                              const float* __restrict__ b2,
                                              float* __restrict__ out) {
    int node = blockIdx.x * 16 + (threadIdx.x >> 4);
    int j = threadIdx.x & 15;
    if (node >= N_NODES) return;
    int end = S[node], start = end - deg[node];
    float4 self = pk2[node];
    float ad = self.w;
    float acc0 = 0.f, acc1 = 0.f, z = 0.f;
    if (j == 0) {
        float ev = self.z + ad;
        ev = fmaxf(ev, NEG * ev);
        float w = __expf(ev);
        acc0 = w * self.x; acc1 = w * self.y; z = w;
    }
    int i = start + j;
    for (; i + 16 < end; i += 32) {
        int s0 = ssrc[i], s1 = ssrc[i + 16];
        float4 q0 = pk2[s0], q1 = pk2[s1];
        float e0 = q0.z + ad; e0 = fmaxf(e0, NEG * e0); float w0 = __expf(e0);
        float e1 = q1.z + ad; e1 = fmaxf(e1, NEG * e1); float w1 = __expf(e1);
        acc0 = fmaf(w0, q0.x, acc0); acc0 = fmaf(w1, q1.x, acc0);
        acc1 = fmaf(w0, q0.y, acc1); acc1 = fmaf(w1, q1.y, acc1);
        z += w0 + w1;
    }
    if (i < end) {
        int s = ssrc[i];
        float4 q = pk2[s];
        float e0 = q.z + ad; e0 = fmaxf(e0, NEG * e0); float w0 = __expf(e0);
        acc0 = fmaf(w0, q.x, acc0);
        acc1 = fmaf(w0, q.y, acc1);
        z += w0;
    }
    #pragma unroll
    for (int m = 1; m < 16; m <<= 1) {
        acc0 += __shfl_xor(acc0, m);
        acc1 += __shfl_xor(acc1, m);
        z    += __shfl_xor(z, m);
    }
    if (j == 0) {
        float v0 = acc0 / z + b2[0];
        float v1 = acc1 / z + b2[1];
        float m = fmaxf(v0, v1);
        float lse = m + logf(__expf(v0 - m) + __expf(v1 - m));
        out[node * 2 + 0] = v0 - lse;
        out[node * 2 + 1] = v1 - lse;
    }
}

extern "C" void kernel_launch(void* const* d_in, const int* in_sizes, int n_in,
                              void* d_out, int out_size, void* d_ws, size_t ws_size,
                              hipStream_t stream) {
    const float* x      = (const float*)d_in[0];
    const int*   ei     = (const int*)d_in[1];
    const float* W1     = (const float*)d_in[2];
    const float* a_src1 = (const float*)d_in[3];
    const float* a_dst1 = (const float*)d_in[4];
    const float* b1     = (const float*)d_in[5];
    const float* W2     = (const float*)d_in[6];
    const float* a_src2 = (const float*)d_in[7];
    const float* a_dst2 = (const float*)d_in[8];
    const float* b2     = (const float*)d_in[9];
    float* out = (float*)d_out;

    float* p = (float*)d_ws;
    float* h1   = p; p += N_NODES * 64;
    float* as1  = p; p += N_NODES * 8;
    float* ad1  = p; p += N_NODES * 8;
    float4* pk2 = (float4*)p; p += N_NODES * 4;
    int* ip = (int*)p;
    int* deg      = ip; ip += N_NODES;
    int* S        = ip; ip += N_NODES;
    int* cursor   = ip; ip += N_NODES;
    int* blockSum = ip; ip += 256;
    int* blockOff = ip; ip += 256;
    int* ssrc     = ip; ip += N_EDGES;
    unsigned short* Wth = (unsigned short*)ip;
    unsigned short* Wtl = Wth + 64 * KPAD;
    unsigned short* xh  = Wtl + 64 * KPAD;           // [N][192] bf16 hi
    unsigned short* xl  = xh + (size_t)N_NODES * KPAD; // [N][192] bf16 lo

    hipMemsetAsync(deg, 0, N_NODES * sizeof(int), stream);

    // CSR build (XCD-range-partitioned hist & scatter)
    k_hist<<<NCHUNK * NXCD, 256, 0, stream>>>(ei, deg);
    k_scan_a<<<NB, 256, 0, stream>>>(deg, S, blockSum);
    k_scan_b<<<1, 256, 0, stream>>>(blockSum, blockOff);
    k_scan_c<<<(N_NODES + 255) / 256, 256, 0, stream>>>(S, deg, blockOff, cursor);
    k_scatter<<<NCHUNK * NXCD, 256, 0, stream>>>(ei, cursor, ssrc);

    // layer 1: convert once, then register-direct MFMA GEMM (no LDS, no barriers)
    k_wconv<<<(64 * KPAD + 255) / 256, 256, 0, stream>>>(W1, Wth, Wtl);
    k_xconv<<<(N_NODES * 24 + 255) / 256, 256, 0, stream>>>(x, xh, xl);
    k_gemm1<<<(N_NODES / 16 + 3) / 4, 256, 0, stream>>>(xh, xl, Wth, Wtl,
                                                        a_src1, a_dst1, h1, as1, ad1);
    k_agg1<<<(N_NODES + 3) / 4, 256, 0, stream>>>(ssrc, S, deg, h1, as1, ad1, b1, W2,
                                                  a_src2, a_dst2, pk2);
    // layer 2 + log_softmax
    k_agg2<<<(N_NODES + 15) / 16, 256, 0, stream>>>(ssrc, S, deg, pk2, b2, out);
}

// Round 7
// 293.681 us; speedup vs baseline: 1.1398x; 1.1398x over previous
//
#include <hip/hip_runtime.h>
#include <math.h>

#define N_NODES 100000
#define N_EDGES 1600000
#define F_IN 165
#define KPAD 192
#define NEG 0.2f
#define NB 98            // ceil(N_NODES / 1024) scan blocks
#define NXCD 8
#define RSZ 12500        // N_NODES / NXCD, exact
#define EPB 1024         // edges per block-chunk (256 thr x 4)
#define NCHUNK ((N_EDGES + EPB - 1) / EPB)

typedef __attribute__((ext_vector_type(8))) short short8v;
typedef __attribute__((ext_vector_type(4))) float f32x4;

static __device__ __forceinline__ unsigned short f2bf(float f) {
    unsigned int u = __float_as_uint(f);
    unsigned int r = (u + 0x7FFFu + ((u >> 16) & 1u)) >> 16;
    return (unsigned short)r;
}
static __device__ __forceinline__ float bf2f(unsigned short b) {
    return __uint_as_float((unsigned int)b << 16);
}

// ---------------- W1 -> transposed bf16 hi/lo [64 cols][192 k] ----------------
__global__ __launch_bounds__(256) void k_wconv(const float* __restrict__ W1,
                                               unsigned short* __restrict__ Wth,
                                               unsigned short* __restrict__ Wtl) {
    int i = blockIdx.x * 256 + threadIdx.x;
    if (i >= 64 * KPAD) return;
    int col = i / KPAD, k = i % KPAD;
    float f = (k < F_IN) ? W1[k * 64 + col] : 0.f;
    unsigned short hi = f2bf(f);
    Wth[i] = hi;
    Wtl[i] = f2bf(f - bf2f(hi));
}

// ---------------- K1: h1 = x @ W1 via bf16 MFMA, register-direct, no LDS ----------------
// 4 waves/block, each wave = 16 rows x 64 cols, no barriers.
// x loaded f32 straight from global, split hi/lo bf16 in-register (truncation;
// residual ~2^-16 relative). h1 stored bf16 (message payload); as1/ad1 f32.
__global__ __launch_bounds__(256) void k_gemm1(const float* __restrict__ x,
                                               const unsigned short* __restrict__ Wth,
                                               const unsigned short* __restrict__ Wtl,
                                               const float* __restrict__ a_src1,
                                               const float* __restrict__ a_dst1,
                                               unsigned short* __restrict__ h1b,
                                               float* __restrict__ as1,
                                               float* __restrict__ ad1) {
    const int t = threadIdx.x;
    const int w = t >> 6, lane = t & 63;
    const int rowblk = blockIdx.x * 4 + w;
    if (rowblk * 16 >= N_NODES) return;
    const int lrow = lane & 15, lk = lane >> 4;
    const int arow = rowblk * 16 + lrow;

    const float* xp = x + (size_t)arow * F_IN + lk * 8;
    const int klo = lk * 8;

    f32x4 acc[4] = {};
    #pragma unroll
    for (int c = 0; c < 6; ++c) {
        // load 8 floats (chunk 5 predicated: k in [160,192) mostly pad)
        float f[8];
        #pragma unroll
        for (int j = 0; j < 8; ++j) {
            int k = c * 32 + klo + j;
            f[j] = (c < 5 || k < F_IN) ? xp[c * 32 + j] : 0.f;
        }
        // split hi/lo bf16 via truncation + v_perm packing
        unsigned int uh[8], ul[8];
        #pragma unroll
        for (int j = 0; j < 8; ++j) {
            unsigned int u = __float_as_uint(f[j]);
            uh[j] = u;
            float lo = f[j] - __uint_as_float(u & 0xFFFF0000u);
            ul[j] = __float_as_uint(lo);
        }
        union { int4 d; short8v s; } ah, al;
        ah.d.x = __builtin_amdgcn_perm(uh[1], uh[0], 0x07060302u);
        ah.d.y = __builtin_amdgcn_perm(uh[3], uh[2], 0x07060302u);
        ah.d.z = __builtin_amdgcn_perm(uh[5], uh[4], 0x07060302u);
        ah.d.w = __builtin_amdgcn_perm(uh[7], uh[6], 0x07060302u);
        al.d.x = __builtin_amdgcn_perm(ul[1], ul[0], 0x07060302u);
        al.d.y = __builtin_amdgcn_perm(ul[3], ul[2], 0x07060302u);
        al.d.z = __builtin_amdgcn_perm(ul[5], ul[4], 0x07060302u);
        al.d.w = __builtin_amdgcn_perm(ul[7], ul[6], 0x07060302u);
        #pragma unroll
        for (int ct = 0; ct < 4; ++ct) {
            const short8v b_h = *(const short8v*)(Wth + (ct * 16 + lrow) * KPAD + c * 32 + klo);
            const short8v b_l = *(const short8v*)(Wtl + (ct * 16 + lrow) * KPAD + c * 32 + klo);
            acc[ct] = __builtin_amdgcn_mfma_f32_16x16x32_bf16(ah.s, b_h, acc[ct], 0, 0, 0);
            acc[ct] = __builtin_amdgcn_mfma_f32_16x16x32_bf16(ah.s, b_l, acc[ct], 0, 0, 0);
            acc[ct] = __builtin_amdgcn_mfma_f32_16x16x32_bf16(al.s, b_h, acc[ct], 0, 0, 0);
        }
    }

    // epilogue: bf16 h1 store + fused per-head alpha reductions (f32)
    #pragma unroll
    for (int ct = 0; ct < 4; ++ct) {
        int colbase = ct * 16 + lrow;
        float av = a_src1[colbase], dv = a_dst1[colbase];
        #pragma unroll
        for (int r = 0; r < 4; ++r) {
            int row = rowblk * 16 + lk * 4 + r;
            float v = acc[ct][r];
            h1b[row * 64 + colbase] = f2bf(v);
            float ps = v * av, pd = v * dv;
            ps += __shfl_xor(ps, 1); ps += __shfl_xor(ps, 2); ps += __shfl_xor(ps, 4);
            pd += __shfl_xor(pd, 1); pd += __shfl_xor(pd, 2); pd += __shfl_xor(pd, 4);
            if ((lane & 7) == 0) {
                int head = ct * 2 + (lrow >> 3);
                as1[row * 8 + head] = ps;
                ad1[row * 8 + head] = pd;
            }
        }
    }
}

// ---------------- CSR build, XCD-range-partitioned ----------------
__global__ __launch_bounds__(256) void k_hist(const int* __restrict__ ei,
                                              int* __restrict__ deg) {
    int r = blockIdx.x & (NXCD - 1);
    int chunk = blockIdx.x >> 3;
    int lo = r * RSZ;
    long e0 = (long)chunk * EPB + threadIdx.x * 4;
    if (e0 >= N_EDGES) return;
    int4 d4 = *(const int4*)(ei + N_EDGES + e0);
    #pragma unroll
    for (int k = 0; k < 4; ++k) {
        int d = (&d4.x)[k];
        if ((unsigned)(d - lo) < RSZ) atomicAdd(&deg[d], 1);
    }
}

__global__ __launch_bounds__(256) void k_scan_a(const int* __restrict__ deg,
                                                int* __restrict__ S,
                                                int* __restrict__ blockSum) {
    __shared__ int lds[256];
    int t = threadIdx.x;
    int base = blockIdx.x * 1024 + t * 4;
    int v[4]; int sum = 0;
    #pragma unroll
    for (int k = 0; k < 4; ++k) { int i = base + k; v[k] = (i < N_NODES) ? deg[i] : 0; sum += v[k]; }
    lds[t] = sum; __syncthreads();
    for (int off = 1; off < 256; off <<= 1) {
        int x = lds[t];
        int y = (t >= off) ? lds[t - off] : 0;
        __syncthreads();
        lds[t] = x + y;
        __syncthreads();
    }
    int run = lds[t] - sum;
    #pragma unroll
    for (int k = 0; k < 4; ++k) {
        run += v[k];
        int i = base + k;
        if (i < N_NODES) S[i] = run;
    }
    if (t == 255) blockSum[blockIdx.x] = lds[255];
}

__global__ __launch_bounds__(256) void k_scan_b(const int* __restrict__ blockSum,
                                                int* __restrict__ blockOff) {
    __shared__ int lds[256];
    int t = threadIdx.x;
    int v = (t < NB) ? blockSum[t] : 0;
    lds[t] = v; __syncthreads();
    for (int off = 1; off < 256; off <<= 1) {
        int x = lds[t];
        int y = (t >= off) ? lds[t - off] : 0;
        __syncthreads();
        lds[t] = x + y;
        __syncthreads();
    }
    if (t < NB) blockOff[t] = lds[t] - v;
}

__global__ __launch_bounds__(256) void k_scan_c(int* __restrict__ S,
                                                const int* __restrict__ deg,
                                                const int* __restrict__ blockOff,
                                                int* __restrict__ cursor) {
    int i = blockIdx.x * 256 + threadIdx.x;
    if (i < N_NODES) {
        int s = S[i] + blockOff[i >> 10];
        S[i] = s;
        cursor[i] = s - deg[i];
    }
}

__global__ __launch_bounds__(256) void k_scatter(const int* __restrict__ ei,
                                                 int* __restrict__ cursor,
                                                 int* __restrict__ ssrc) {
    int r = blockIdx.x & (NXCD - 1);
    int chunk = blockIdx.x >> 3;
    int lo = r * RSZ;
    long e0 = (long)chunk * EPB + threadIdx.x * 4;
    if (e0 >= N_EDGES) return;
    int4 s4 = *(const int4*)(ei + e0);
    int4 d4 = *(const int4*)(ei + N_EDGES + e0);
    #pragma unroll
    for (int k = 0; k < 4; ++k) {
        int d = (&d4.x)[k];
        if ((unsigned)(d - lo) < RSZ) {
            int pos = atomicAdd(&cursor[d], 1);
            ssrc[pos] = (&s4.x)[k];
        }
    }
}

// ---------------- layer-1 aggregate + elu + @W2 + alpha2, fused ----------------
// one wave per node; lane = channel; bf16 message gather (128 B/edge).
__global__ __launch_bounds__(256) void k_agg1(const int* __restrict__ ssrc,
                                              const int* __restrict__ S,
                                              const int* __restrict__ deg,
                                              const unsigned short* __restrict__ h1b,
                                              const float* __restrict__ as1,
                                              const float* __restrict__ ad1,
                                              const float* __restrict__ b1,
                                              const float* __restrict__ W2,
                                              const float* __restrict__ a_src2,
                                              const float* __restrict__ a_dst2,
                                              float4* __restrict__ pk2) {
    int node = blockIdx.x * 4 + (threadIdx.x >> 6);
    int lane = threadIdx.x & 63;
    if (node >= N_NODES) return;
    int h = lane >> 3;
    int end = S[node], start = end - deg[node];
    float adh = ad1[node * 8 + h];
    float ev = as1[node * 8 + h] + adh;
    ev = fmaxf(ev, NEG * ev);
    float w = __expf(ev);
    float acc = w * bf2f(h1b[node * 64 + lane]);
    float z = w;

    for (int c = start; c < end; c += 64) {
        int cnt = end - c; if (cnt > 64) cnt = 64;
        int sidx = (lane < cnt) ? ssrc[c + lane] : 0;
        int k = 0;
        for (; k + 4 <= cnt; k += 4) {
            int s0 = __shfl(sidx, k);
            int s1 = __shfl(sidx, k + 1);
            int s2 = __shfl(sidx, k + 2);
            int s3 = __shfl(sidx, k + 3);
            float a0 = as1[s0 * 8 + h];
            float a1 = as1[s1 * 8 + h];
            float a2 = as1[s2 * 8 + h];
            float a3 = as1[s3 * 8 + h];
            float g0 = bf2f(h1b[s0 * 64 + lane]);
            float g1 = bf2f(h1b[s1 * 64 + lane]);
            float g2 = bf2f(h1b[s2 * 64 + lane]);
            float g3 = bf2f(h1b[s3 * 64 + lane]);
            float e0 = a0 + adh; e0 = fmaxf(e0, NEG * e0); float w0 = __expf(e0);
            float e1 = a1 + adh; e1 = fmaxf(e1, NEG * e1); float w1 = __expf(e1);
            float e2 = a2 + adh; e2 = fmaxf(e2, NEG * e2); float w2 = __expf(e2);
            float e3 = a3 + adh; e3 = fmaxf(e3, NEG * e3); float w3 = __expf(e3);
            acc = fmaf(w0, g0, acc); acc = fmaf(w1, g1, acc);
            acc = fmaf(w2, g2, acc); acc = fmaf(w3, g3, acc);
            z += (w0 + w1) + (w2 + w3);
        }
        for (; k < cnt; ++k) {
            int s = __shfl(sidx, k);
            float a = as1[s * 8 + h];
            float g = bf2f(h1b[s * 64 + lane]);
            float e2 = a + adh; e2 = fmaxf(e2, NEG * e2);
            float ww = __expf(e2);
            acc = fmaf(ww, g, acc);
            z += ww;
        }
    }

    float o = acc / z + b1[lane];
    o = o > 0.f ? o : expm1f(o);
    float p0 = o * W2[lane * 2 + 0];
    float p1 = o * W2[lane * 2 + 1];
    #pragma unroll
    for (int m = 1; m < 64; m <<= 1) { p0 += __shfl_xor(p0, m); p1 += __shfl_xor(p1, m); }
    if (lane == 0) {
        pk2[node] = make_float4(p0, p1,
                                p0 * a_src2[0] + p1 * a_src2[1],
                                p0 * a_dst2[0] + p1 * a_dst2[1]);
    }
}

// ---------------- layer-2 aggregate + log_softmax, fused ----------------
__global__ __launch_bounds__(256) void k_agg2(const int* __restrict__ ssrc,
                                              const int* __restrict__ S,
                                              const int* __restrict__ deg,
                                              const float4* __restrict__ pk2,
                                              const float* __restrict__ b2,
                                              float* __restrict__ out) {
    int node = blockIdx.x * 16 + (threadIdx.x >> 4);
    int j = threadIdx.x & 15;
    if (node >= N_NODES) return;
    int end = S[node], start = end - deg[node];
    float4 self = pk2[node];
    float ad = self.w;
    float acc0 = 0.f, acc1 = 0.f, z = 0.f;
    if (j == 0) {
        float ev = self.z + ad;
        ev = fmaxf(ev, NEG * ev);
        float w = __expf(ev);
        acc0 = w * self.x; acc1 = w * self.y; z = w;
    }
    int i = start + j;
    for (; i + 16 < end; i += 32) {
        int s0 = ssrc[i], s1 = ssrc[i + 16];
        float4 q0 = pk2[s0], q1 = pk2[s1];
        float e0 = q0.z + ad; e0 = fmaxf(e0, NEG * e0); float w0 = __expf(e0);
        float e1 = q1.z + ad; e1 = fmaxf(e1, NEG * e1); float w1 = __expf(e1);
        acc0 = fmaf(w0, q0.x, acc0); acc0 = fmaf(w1, q1.x, acc0);
        acc1 = fmaf(w0, q0.y, acc1); acc1 = fmaf(w1, q1.y, acc1);
        z += w0 + w1;
    }
    if (i < end) {
        int s = ssrc[i];
        float4 q = pk2[s];
        float e0 = q.z + ad; e0 = fmaxf(e0, NEG * e0); float w0 = __expf(e0);
        acc0 = fmaf(w0, q.x, acc0);
        acc1 = fmaf(w0, q.y, acc1);
        z += w0;
    }
    #pragma unroll
    for (int m = 1; m < 16; m <<= 1) {
        acc0 += __shfl_xor(acc0, m);
        acc1 += __shfl_xor(acc1, m);
        z    += __shfl_xor(z, m);
    }
    if (j == 0) {
        float v0 = acc0 / z + b2[0];
        float v1 = acc1 / z + b2[1];
        float m = fmaxf(v0, v1);
        float lse = m + logf(__expf(v0 - m) + __expf(v1 - m));
        out[node * 2 + 0] = v0 - lse;
        out[node * 2 + 1] = v1 - lse;
    }
}

extern "C" void kernel_launch(void* const* d_in, const int* in_sizes, int n_in,
                              void* d_out, int out_size, void* d_ws, size_t ws_size,
                              hipStream_t stream) {
    const float* x      = (const float*)d_in[0];
    const int*   ei     = (const int*)d_in[1];
    const float* W1     = (const float*)d_in[2];
    const float* a_src1 = (const float*)d_in[3];
    const float* a_dst1 = (const float*)d_in[4];
    const float* b1     = (const float*)d_in[5];
    const float* W2     = (const float*)d_in[6];
    const float* a_src2 = (const float*)d_in[7];
    const float* a_dst2 = (const float*)d_in[8];
    const float* b2     = (const float*)d_in[9];
    float* out = (float*)d_out;

    float* p = (float*)d_ws;
    unsigned short* h1b = (unsigned short*)p; p += N_NODES * 32;  // bf16 [N][64]
    float* as1  = p; p += N_NODES * 8;
    float* ad1  = p; p += N_NODES * 8;
    float4* pk2 = (float4*)p; p += N_NODES * 4;
    int* ip = (int*)p;
    int* deg      = ip; ip += N_NODES;
    int* S        = ip; ip += N_NODES;
    int* cursor   = ip; ip += N_NODES;
    int* blockSum = ip; ip += 256;
    int* blockOff = ip; ip += 256;
    int* ssrc     = ip; ip += N_EDGES;
    unsigned short* Wth = (unsigned short*)ip;
    unsigned short* Wtl = Wth + 64 * KPAD;

    hipMemsetAsync(deg, 0, N_NODES * sizeof(int), stream);

    // CSR build (XCD-range-partitioned hist & scatter)
    k_hist<<<NCHUNK * NXCD, 256, 0, stream>>>(ei, deg);
    k_scan_a<<<NB, 256, 0, stream>>>(deg, S, blockSum);
    k_scan_b<<<1, 256, 0, stream>>>(blockSum, blockOff);
    k_scan_c<<<(N_NODES + 255) / 256, 256, 0, stream>>>(S, deg, blockOff, cursor);
    k_scatter<<<NCHUNK * NXCD, 256, 0, stream>>>(ei, cursor, ssrc);

    // layer 1: register-direct MFMA GEMM, x converted in-register
    k_wconv<<<(64 * KPAD + 255) / 256, 256, 0, stream>>>(W1, Wth, Wtl);
    k_gemm1<<<(N_NODES / 16 + 3) / 4, 256, 0, stream>>>(x, Wth, Wtl,
                                                        a_src1, a_dst1, h1b, as1, ad1);
    k_agg1<<<(N_NODES + 3) / 4, 256, 0, stream>>>(ssrc, S, deg, h1b, as1, ad1, b1, W2,
                                                  a_src2, a_dst2, pk2);
    // layer 2 + log_softmax
    k_agg2<<<(N_NODES + 15) / 16, 256, 0, stream>>>(ssrc, S, deg, pk2, b2, out);
}

// Round 8
// 282.560 us; speedup vs baseline: 1.1846x; 1.0394x over previous
//
#include <hip/hip_runtime.h>
#include <math.h>

#define N_NODES 100000
#define N_EDGES 1600000
#define F_IN 165
#define KPAD 192
#define NEG 0.2f
#define NB 98            // ceil(N_NODES / 1024) scan blocks
#define NXCD 8
#define RSZ 12500        // N_NODES / NXCD, exact
#define EPB 1024         // edges per block-chunk (256 thr x 4)
#define NCHUNK ((N_EDGES + EPB - 1) / EPB)

typedef __attribute__((ext_vector_type(8))) short short8v;
typedef __attribute__((ext_vector_type(4))) float f32x4;

static __device__ __forceinline__ unsigned short f2bf(float f) {
    unsigned int u = __float_as_uint(f);
    unsigned int r = (u + 0x7FFFu + ((u >> 16) & 1u)) >> 16;
    return (unsigned short)r;
}
static __device__ __forceinline__ float bf2f(unsigned short b) {
    return __uint_as_float((unsigned int)b << 16);
}

// ---------------- W1 -> transposed bf16 hi/lo [64 cols][192 k] ----------------
__global__ __launch_bounds__(256) void k_wconv(const float* __restrict__ W1,
                                               unsigned short* __restrict__ Wth,
                                               unsigned short* __restrict__ Wtl) {
    int i = blockIdx.x * 256 + threadIdx.x;
    if (i >= 64 * KPAD) return;
    int col = i / KPAD, k = i % KPAD;
    float f = (k < F_IN) ? W1[k * 64 + col] : 0.f;
    unsigned short hi = f2bf(f);
    Wth[i] = hi;
    Wtl[i] = f2bf(f - bf2f(hi));
}

// ---------------- K1: h1 = x @ W1 via bf16 MFMA, register-direct, no LDS ----------------
__global__ __launch_bounds__(256) void k_gemm1(const float* __restrict__ x,
                                               const unsigned short* __restrict__ Wth,
                                               const unsigned short* __restrict__ Wtl,
                                               const float* __restrict__ a_src1,
                                               const float* __restrict__ a_dst1,
                                               unsigned short* __restrict__ h1b,
                                               float* __restrict__ as1,
                                               float* __restrict__ ad1) {
    const int t = threadIdx.x;
    const int w = t >> 6, lane = t & 63;
    const int rowblk = blockIdx.x * 4 + w;
    if (rowblk * 16 >= N_NODES) return;
    const int lrow = lane & 15, lk = lane >> 4;
    const int arow = rowblk * 16 + lrow;

    const float* xp = x + (size_t)arow * F_IN + lk * 8;
    const int klo = lk * 8;

    f32x4 acc[4] = {};
    #pragma unroll
    for (int c = 0; c < 6; ++c) {
        float f[8];
        #pragma unroll
        for (int j = 0; j < 8; ++j) {
            int k = c * 32 + klo + j;
            f[j] = (c < 5 || k < F_IN) ? xp[c * 32 + j] : 0.f;
        }
        unsigned int uh[8], ul[8];
        #pragma unroll
        for (int j = 0; j < 8; ++j) {
            unsigned int u = __float_as_uint(f[j]);
            uh[j] = u;
            float lo = f[j] - __uint_as_float(u & 0xFFFF0000u);
            ul[j] = __float_as_uint(lo);
        }
        union { int4 d; short8v s; } ah, al;
        ah.d.x = __builtin_amdgcn_perm(uh[1], uh[0], 0x07060302u);
        ah.d.y = __builtin_amdgcn_perm(uh[3], uh[2], 0x07060302u);
        ah.d.z = __builtin_amdgcn_perm(uh[5], uh[4], 0x07060302u);
        ah.d.w = __builtin_amdgcn_perm(uh[7], uh[6], 0x07060302u);
        al.d.x = __builtin_amdgcn_perm(ul[1], ul[0], 0x07060302u);
        al.d.y = __builtin_amdgcn_perm(ul[3], ul[2], 0x07060302u);
        al.d.z = __builtin_amdgcn_perm(ul[5], ul[4], 0x07060302u);
        al.d.w = __builtin_amdgcn_perm(ul[7], ul[6], 0x07060302u);
        #pragma unroll
        for (int ct = 0; ct < 4; ++ct) {
            const short8v b_h = *(const short8v*)(Wth + (ct * 16 + lrow) * KPAD + c * 32 + klo);
            const short8v b_l = *(const short8v*)(Wtl + (ct * 16 + lrow) * KPAD + c * 32 + klo);
            acc[ct] = __builtin_amdgcn_mfma_f32_16x16x32_bf16(ah.s, b_h, acc[ct], 0, 0, 0);
            acc[ct] = __builtin_amdgcn_mfma_f32_16x16x32_bf16(ah.s, b_l, acc[ct], 0, 0, 0);
            acc[ct] = __builtin_amdgcn_mfma_f32_16x16x32_bf16(al.s, b_h, acc[ct], 0, 0, 0);
        }
    }

    #pragma unroll
    for (int ct = 0; ct < 4; ++ct) {
        int colbase = ct * 16 + lrow;
        float av = a_src1[colbase], dv = a_dst1[colbase];
        #pragma unroll
        for (int r = 0; r < 4; ++r) {
            int row = rowblk * 16 + lk * 4 + r;
            float v = acc[ct][r];
            h1b[row * 64 + colbase] = f2bf(v);
            float ps = v * av, pd = v * dv;
            ps += __shfl_xor(ps, 1); ps += __shfl_xor(ps, 2); ps += __shfl_xor(ps, 4);
            pd += __shfl_xor(pd, 1); pd += __shfl_xor(pd, 2); pd += __shfl_xor(pd, 4);
            if ((lane & 7) == 0) {
                int head = ct * 2 + (lrow >> 3);
                as1[row * 8 + head] = ps;
                ad1[row * 8 + head] = pd;
            }
        }
    }
}

// ---------------- CSR build, XCD-range-partitioned ----------------
__global__ __launch_bounds__(256) void k_hist(const int* __restrict__ ei,
                                              int* __restrict__ deg) {
    int r = blockIdx.x & (NXCD - 1);
    int chunk = blockIdx.x >> 3;
    int lo = r * RSZ;
    long e0 = (long)chunk * EPB + threadIdx.x * 4;
    if (e0 >= N_EDGES) return;
    int4 d4 = *(const int4*)(ei + N_EDGES + e0);
    #pragma unroll
    for (int k = 0; k < 4; ++k) {
        int d = (&d4.x)[k];
        if ((unsigned)(d - lo) < RSZ) atomicAdd(&deg[d], 1);
    }
}

__global__ __launch_bounds__(256) void k_scan_a(const int* __restrict__ deg,
                                                int* __restrict__ S,
                                                int* __restrict__ blockSum) {
    __shared__ int lds[256];
    int t = threadIdx.x;
    int base = blockIdx.x * 1024 + t * 4;
    int v[4]; int sum = 0;
    #pragma unroll
    for (int k = 0; k < 4; ++k) { int i = base + k; v[k] = (i < N_NODES) ? deg[i] : 0; sum += v[k]; }
    lds[t] = sum; __syncthreads();
    for (int off = 1; off < 256; off <<= 1) {
        int x = lds[t];
        int y = (t >= off) ? lds[t - off] : 0;
        __syncthreads();
        lds[t] = x + y;
        __syncthreads();
    }
    int run = lds[t] - sum;
    #pragma unroll
    for (int k = 0; k < 4; ++k) {
        run += v[k];
        int i = base + k;
        if (i < N_NODES) S[i] = run;
    }
    if (t == 255) blockSum[blockIdx.x] = lds[255];
}

__global__ __launch_bounds__(256) void k_scan_b(const int* __restrict__ blockSum,
                                                int* __restrict__ blockOff) {
    __shared__ int lds[256];
    int t = threadIdx.x;
    int v = (t < NB) ? blockSum[t] : 0;
    lds[t] = v; __syncthreads();
    for (int off = 1; off < 256; off <<= 1) {
        int x = lds[t];
        int y = (t >= off) ? lds[t - off] : 0;
        __syncthreads();
        lds[t] = x + y;
        __syncthreads();
    }
    if (t < NB) blockOff[t] = lds[t] - v;
}

__global__ __launch_bounds__(256) void k_scan_c(int* __restrict__ S,
                                                const int* __restrict__ deg,
                                                const int* __restrict__ blockOff,
                                                int* __restrict__ cursor) {
    int i = blockIdx.x * 256 + threadIdx.x;
    if (i < N_NODES) {
        int s = S[i] + blockOff[i >> 10];
        S[i] = s;
        cursor[i] = s - deg[i];
    }
}

__global__ __launch_bounds__(256) void k_scatter(const int* __restrict__ ei,
                                                 int* __restrict__ cursor,
                                                 int* __restrict__ ssrc) {
    int r = blockIdx.x & (NXCD - 1);
    int chunk = blockIdx.x >> 3;
    int lo = r * RSZ;
    long e0 = (long)chunk * EPB + threadIdx.x * 4;
    if (e0 >= N_EDGES) return;
    int4 s4 = *(const int4*)(ei + e0);
    int4 d4 = *(const int4*)(ei + N_EDGES + e0);
    #pragma unroll
    for (int k = 0; k < 4; ++k) {
        int d = (&d4.x)[k];
        if ((unsigned)(d - lo) < RSZ) {
            int pos = atomicAdd(&cursor[d], 1);
            ssrc[pos] = (&s4.x)[k];
        }
    }
}

// ---------------- layer-1 aggregate + elu + @W2 + alpha2, fused ----------------
// one wave per node. Two-layout inner loop per 8-edge group:
//   w-pass:  lane = (edge_local e<<3)|head -> each w computed ONCE (8x less exp)
//   agg-pass: lane = channel; s via readlane (SGPR base, no per-lane addr VALU),
//             w via one ds_bpermute, then lshl+fma.
__global__ __launch_bounds__(256) void k_agg1(const int* __restrict__ ssrc,
                                              const int* __restrict__ S,
                                              const int* __restrict__ deg,
                                              const unsigned short* __restrict__ h1b,
                                              const float* __restrict__ as1,
                                              const float* __restrict__ ad1,
                                              const float* __restrict__ b1,
                                              const float* __restrict__ W2,
                                              const float* __restrict__ a_src2,
                                              const float* __restrict__ a_dst2,
                                              float4* __restrict__ pk2) {
    int node = blockIdx.x * 4 + (threadIdx.x >> 6);
    int lane = threadIdx.x & 63;
    if (node >= N_NODES) return;
    int h  = lane >> 3;   // head, channel layout
    int hw = lane & 7;    // head, w layout
    int el = lane >> 3;   // edge-local slot, w layout
    int end = S[node], start = end - deg[node];

    float adh  = ad1[node * 8 + h];
    float adhw = ad1[node * 8 + hw];

    // self loop (channel layout)
    float ev = as1[node * 8 + h] + adh;
    ev = fmaxf(ev, NEG * ev);
    float wself = __expf(ev);
    float acc = wself * bf2f(h1b[node * 64 + lane]);
    float zw = 0.f;   // z partials in w layout

    for (int c = start; c < end; c += 64) {
        int cnt = end - c; if (cnt > 64) cnt = 64;
        int sidx = (lane < cnt) ? ssrc[c + lane] : 0;
        int ng = (cnt + 7) >> 3;
        for (int g = 0; g < ng; ++g) {
            // ---- w-pass: this lane owns (edge g*8+el, head hw) ----
            int eidx = g * 8 + el;
            int se = __shfl(sidx, eidx);           // 0 if eidx >= cnt
            float a = as1[se * 8 + hw];
            float e0 = a + adhw;
            e0 = fmaxf(e0, NEG * e0);
            float wv = (eidx < cnt) ? __expf(e0) : 0.f;
            zw += wv;
            // ---- agg-pass: lane = channel ----
            #pragma unroll
            for (int e = 0; e < 8; ++e) {
                int sb = __builtin_amdgcn_readlane(sidx, g * 8 + e);  // uniform -> SGPR
                float wb = __shfl(wv, e * 8 + el);                    // w[e][h]
                float gm = bf2f(h1b[sb * 64 + lane]);                 // saddr + lane*2
                acc = fmaf(wb, gm, acc);
            }
        }
    }

    // finish z: reduce w-layout partials over edge slots, broadcast to channels
    zw += __shfl_xor(zw, 8); zw += __shfl_xor(zw, 16); zw += __shfl_xor(zw, 32);
    float z = __shfl(zw, h) + wself;

    float o = acc / z + b1[lane];
    o = o > 0.f ? o : expm1f(o);
    float p0 = o * W2[lane * 2 + 0];
    float p1 = o * W2[lane * 2 + 1];
    #pragma unroll
    for (int m = 1; m < 64; m <<= 1) { p0 += __shfl_xor(p0, m); p1 += __shfl_xor(p1, m); }
    if (lane == 0) {
        pk2[node] = make_float4(p0, p1,
                                p0 * a_src2[0] + p1 * a_src2[1],
                                p0 * a_dst2[0] + p1 * a_dst2[1]);
    }
}

// ---------------- layer-2 aggregate + log_softmax, fused ----------------
__global__ __launch_bounds__(256) void k_agg2(const int* __restrict__ ssrc,
                                              const int* __restrict__ S,
                                              const int* __restrict__ deg,
                                              const float4* __restrict__ pk2,
                                              const float* __restrict__ b2,
                                              float* __restrict__ out) {
    int node = blockIdx.x * 16 + (threadIdx.x >> 4);
    int j = threadIdx.x & 15;
    if (node >= N_NODES) return;
    int end = S[node], start = end - deg[node];
    float4 self = pk2[node];
    float ad = self.w;
    float acc0 = 0.f, acc1 = 0.f, z = 0.f;
    if (j == 0) {
        float ev = self.z + ad;
        ev = fmaxf(ev, NEG * ev);
        float w = __expf(ev);
        acc0 = w * self.x; acc1 = w * self.y; z = w;
    }
    int i = start + j;
    for (; i + 16 < end; i += 32) {
        int s0 = ssrc[i], s1 = ssrc[i + 16];
        float4 q0 = pk2[s0], q1 = pk2[s1];
        float e0 = q0.z + ad; e0 = fmaxf(e0, NEG * e0); float w0 = __expf(e0);
        float e1 = q1.z + ad; e1 = fmaxf(e1, NEG * e1); float w1 = __expf(e1);
        acc0 = fmaf(w0, q0.x, acc0); acc0 = fmaf(w1, q1.x, acc0);
        acc1 = fmaf(w0, q0.y, acc1); acc1 = fmaf(w1, q1.y, acc1);
        z += w0 + w1;
    }
    if (i < end) {
        int s = ssrc[i];
        float4 q = pk2[s];
        float e0 = q.z + ad; e0 = fmaxf(e0, NEG * e0); float w0 = __expf(e0);
        acc0 = fmaf(w0, q.x, acc0);
        acc1 = fmaf(w0, q.y, acc1);
        z += w0;
    }
    #pragma unroll
    for (int m = 1; m < 16; m <<= 1) {
        acc0 += __shfl_xor(acc0, m);
        acc1 += __shfl_xor(acc1, m);
        z    += __shfl_xor(z, m);
    }
    if (j == 0) {
        float v0 = acc0 / z + b2[0];
        float v1 = acc1 / z + b2[1];
        float m = fmaxf(v0, v1);
        float lse = m + logf(__expf(v0 - m) + __expf(v1 - m));
        out[node * 2 + 0] = v0 - lse;
        out[node * 2 + 1] = v1 - lse;
    }
}

extern "C" void kernel_launch(void* const* d_in, const int* in_sizes, int n_in,
                              void* d_out, int out_size, void* d_ws, size_t ws_size,
                              hipStream_t stream) {
    const float* x      = (const float*)d_in[0];
    const int*   ei     = (const int*)d_in[1];
    const float* W1     = (const float*)d_in[2];
    const float* a_src1 = (const float*)d_in[3];
    const float* a_dst1 = (const float*)d_in[4];
    const float* b1     = (const float*)d_in[5];
    const float* W2     = (const float*)d_in[6];
    const float* a_src2 = (const float*)d_in[7];
    const float* a_dst2 = (const float*)d_in[8];
    const float* b2     = (const float*)d_in[9];
    float* out = (float*)d_out;

    float* p = (float*)d_ws;
    unsigned short* h1b = (unsigned short*)p; p += N_NODES * 32;  // bf16 [N][64]
    float* as1  = p; p += N_NODES * 8;
    float* ad1  = p; p += N_NODES * 8;
    float4* pk2 = (float4*)p; p += N_NODES * 4;
    int* ip = (int*)p;
    int* deg      = ip; ip += N_NODES;
    int* S        = ip; ip += N_NODES;
    int* cursor   = ip; ip += N_NODES;
    int* blockSum = ip; ip += 256;
    int* blockOff = ip; ip += 256;
    int* ssrc     = ip; ip += N_EDGES;
    unsigned short* Wth = (unsigned short*)ip;
    unsigned short* Wtl = Wth + 64 * KPAD;

    hipMemsetAsync(deg, 0, N_NODES * sizeof(int), stream);

    // CSR build (XCD-range-partitioned hist & scatter)
    k_hist<<<NCHUNK * NXCD, 256, 0, stream>>>(ei, deg);
    k_scan_a<<<NB, 256, 0, stream>>>(deg, S, blockSum);
    k_scan_b<<<1, 256, 0, stream>>>(blockSum, blockOff);
    k_scan_c<<<(N_NODES + 255) / 256, 256, 0, stream>>>(S, deg, blockOff, cursor);
    k_scatter<<<NCHUNK * NXCD, 256, 0, stream>>>(ei, cursor, ssrc);

    // layer 1: register-direct MFMA GEMM, x converted in-register
    k_wconv<<<(64 * KPAD + 255) / 256, 256, 0, stream>>>(W1, Wth, Wtl);
    k_gemm1<<<(N_NODES / 16 + 3) / 4, 256, 0, stream>>>(x, Wth, Wtl,
                                                        a_src1, a_dst1, h1b, as1, ad1);
    k_agg1<<<(N_NODES + 3) / 4, 256, 0, stream>>>(ssrc, S, deg, h1b, as1, ad1, b1, W2,
                                                  a_src2, a_dst2, pk2);
    // layer 2 + log_softmax
    k_agg2<<<(N_NODES + 15) / 16, 256, 0, stream>>>(ssrc, S, deg, pk2, b2, out);
}

// Round 9
// 282.319 us; speedup vs baseline: 1.1856x; 1.0009x over previous
//
#include <hip/hip_runtime.h>
#include <math.h>

#define N_NODES 100000
#define N_EDGES 1600000
#define F_IN 165
#define KPAD 192
#define NEG 0.2f
#define NB 98            // ceil(N_NODES / 1024) scan blocks
#define BK_SHIFT 10
#define NBK 98           // ceil(N_NODES / 1024) dst buckets
#define PART_EPB 1024    // edges per k_part block
#define NPART ((N_EDGES + PART_EPB - 1) / PART_EPB)
#define BCH 5            // max 4096-record chunks per bucket (mean 16.3K, sd 127)
#define DH_GRID (8 * BCH * ((NBK + 7) / 8))

typedef __attribute__((ext_vector_type(8))) short short8v;
typedef __attribute__((ext_vector_type(4))) float f32x4;

static __device__ __forceinline__ unsigned short f2bf(float f) {
    unsigned int u = __float_as_uint(f);
    unsigned int r = (u + 0x7FFFu + ((u >> 16) & 1u)) >> 16;
    return (unsigned short)r;
}
static __device__ __forceinline__ float bf2f(unsigned short b) {
    return __uint_as_float((unsigned int)b << 16);
}

// ---------------- W1 -> transposed bf16 hi/lo [64 cols][192 k] ----------------
__global__ __launch_bounds__(256) void k_wconv(const float* __restrict__ W1,
                                               unsigned short* __restrict__ Wth,
                                               unsigned short* __restrict__ Wtl) {
    int i = blockIdx.x * 256 + threadIdx.x;
    if (i >= 64 * KPAD) return;
    int col = i / KPAD, k = i % KPAD;
    float f = (k < F_IN) ? W1[k * 64 + col] : 0.f;
    unsigned short hi = f2bf(f);
    Wth[i] = hi;
    Wtl[i] = f2bf(f - bf2f(hi));
}

// ---------------- K1: h1 = x @ W1 via bf16 MFMA, register-direct, no LDS ----------------
__global__ __launch_bounds__(256) void k_gemm1(const float* __restrict__ x,
                                               const unsigned short* __restrict__ Wth,
                                               const unsigned short* __restrict__ Wtl,
                                               const float* __restrict__ a_src1,
                                               const float* __restrict__ a_dst1,
                                               unsigned short* __restrict__ h1b,
                                               float* __restrict__ as1,
                                               float* __restrict__ ad1) {
    const int t = threadIdx.x;
    const int w = t >> 6, lane = t & 63;
    const int rowblk = blockIdx.x * 4 + w;
    if (rowblk * 16 >= N_NODES) return;
    const int lrow = lane & 15, lk = lane >> 4;
    const int arow = rowblk * 16 + lrow;

    const float* xp = x + (size_t)arow * F_IN + lk * 8;
    const int klo = lk * 8;

    f32x4 acc[4] = {};
    #pragma unroll
    for (int c = 0; c < 6; ++c) {
        float f[8];
        #pragma unroll
        for (int j = 0; j < 8; ++j) {
            int k = c * 32 + klo + j;
            f[j] = (c < 5 || k < F_IN) ? xp[c * 32 + j] : 0.f;
        }
        unsigned int uh[8], ul[8];
        #pragma unroll
        for (int j = 0; j < 8; ++j) {
            unsigned int u = __float_as_uint(f[j]);
            uh[j] = u;
            float lo = f[j] - __uint_as_float(u & 0xFFFF0000u);
            ul[j] = __float_as_uint(lo);
        }
        union { int4 d; short8v s; } ah, al;
        ah.d.x = __builtin_amdgcn_perm(uh[1], uh[0], 0x07060302u);
        ah.d.y = __builtin_amdgcn_perm(uh[3], uh[2], 0x07060302u);
        ah.d.z = __builtin_amdgcn_perm(uh[5], uh[4], 0x07060302u);
        ah.d.w = __builtin_amdgcn_perm(uh[7], uh[6], 0x07060302u);
        al.d.x = __builtin_amdgcn_perm(ul[1], ul[0], 0x07060302u);
        al.d.y = __builtin_amdgcn_perm(ul[3], ul[2], 0x07060302u);
        al.d.z = __builtin_amdgcn_perm(ul[5], ul[4], 0x07060302u);
        al.d.w = __builtin_amdgcn_perm(ul[7], ul[6], 0x07060302u);
        #pragma unroll
        for (int ct = 0; ct < 4; ++ct) {
            const short8v b_h = *(const short8v*)(Wth + (ct * 16 + lrow) * KPAD + c * 32 + klo);
            const short8v b_l = *(const short8v*)(Wtl + (ct * 16 + lrow) * KPAD + c * 32 + klo);
            acc[ct] = __builtin_amdgcn_mfma_f32_16x16x32_bf16(ah.s, b_h, acc[ct], 0, 0, 0);
            acc[ct] = __builtin_amdgcn_mfma_f32_16x16x32_bf16(ah.s, b_l, acc[ct], 0, 0, 0);
            acc[ct] = __builtin_amdgcn_mfma_f32_16x16x32_bf16(al.s, b_h, acc[ct], 0, 0, 0);
        }
    }

    #pragma unroll
    for (int ct = 0; ct < 4; ++ct) {
        int colbase = ct * 16 + lrow;
        float av = a_src1[colbase], dv = a_dst1[colbase];
        #pragma unroll
        for (int r = 0; r < 4; ++r) {
            int row = rowblk * 16 + lk * 4 + r;
            float v = acc[ct][r];
            h1b[row * 64 + colbase] = f2bf(v);
            float ps = v * av, pd = v * dv;
            ps += __shfl_xor(ps, 1); ps += __shfl_xor(ps, 2); ps += __shfl_xor(ps, 4);
            pd += __shfl_xor(pd, 1); pd += __shfl_xor(pd, 2); pd += __shfl_xor(pd, 4);
            if ((lane & 7) == 0) {
                int head = ct * 2 + (lrow >> 3);
                as1[row * 8 + head] = ps;
                ad1[row * 8 + head] = pd;
            }
        }
    }
}

// ---------------- CSR build: two-phase multisplit ----------------
// Phase 0: bucket histogram (bucket = dst >> 10), LDS-binned.
__global__ __launch_bounds__(256) void k_bhist(const int* __restrict__ ei,
                                               int* __restrict__ bcnt) {
    __shared__ int cnt[NBK];
    int t = threadIdx.x;
    for (int i = t; i < NBK; i += 256) cnt[i] = 0;
    __syncthreads();
    long base = (long)blockIdx.x * 4096 + t * 4;
    #pragma unroll
    for (int q = 0; q < 4; ++q) {
        long e0 = base + q * 1024;
        if (e0 < N_EDGES) {
            int4 d4 = *(const int4*)(ei + N_EDGES + e0);
            atomicAdd(&cnt[d4.x >> BK_SHIFT], 1);
            atomicAdd(&cnt[d4.y >> BK_SHIFT], 1);
            atomicAdd(&cnt[d4.z >> BK_SHIFT], 1);
            atomicAdd(&cnt[d4.w >> BK_SHIFT], 1);
        }
    }
    __syncthreads();
    for (int i = t; i < NBK; i += 256) if (cnt[i]) atomicAdd(&bcnt[i], cnt[i]);
}

__global__ __launch_bounds__(128) void k_bscan(const int* __restrict__ bcnt,
                                               int* __restrict__ bbase,
                                               int* __restrict__ gcur) {
    __shared__ int lds[128];
    int t = threadIdx.x;
    int v = (t < NBK) ? bcnt[t] : 0;
    lds[t] = v; __syncthreads();
    for (int off = 1; off < 128; off <<= 1) {
        int x = lds[t];
        int y = (t >= off) ? lds[t - off] : 0;
        __syncthreads();
        lds[t] = x + y;
        __syncthreads();
    }
    if (t < NBK) { int ex = lds[t] - v; bbase[t] = ex; gcur[t] = ex; }
}

// Phase 1: partition (s,d) records into bucket regions; block-local LDS sort
// by bucket so global writes are contiguous runs (near-full-line).
__global__ __launch_bounds__(256) void k_part(const int* __restrict__ ei,
                                              int* __restrict__ gcur,
                                              int2* __restrict__ rec) {
    __shared__ int cnt[NBK], lo[NBK], gb[NBK];
    __shared__ int sc[128];
    __shared__ int sS[PART_EPB], dS[PART_EPB], gS[PART_EPB];
    int t = threadIdx.x;
    for (int i = t; i < NBK; i += 256) cnt[i] = 0;
    __syncthreads();
    long e0 = (long)blockIdx.x * PART_EPB + t * 4;
    bool val = e0 < N_EDGES;
    int4 s4, d4; int rk[4], bk[4];
    if (val) {
        s4 = *(const int4*)(ei + e0);
        d4 = *(const int4*)(ei + N_EDGES + e0);
        #pragma unroll
        for (int k = 0; k < 4; ++k) {
            bk[k] = (&d4.x)[k] >> BK_SHIFT;
            rk[k] = atomicAdd(&cnt[bk[k]], 1);
        }
    }
    __syncthreads();
    if (t < 128) sc[t] = (t < NBK) ? cnt[t] : 0;
    __syncthreads();
    for (int off = 1; off < 128; off <<= 1) {
        int xv = 0, y = 0;
        if (t < 128) { xv = sc[t]; if (t >= off) y = sc[t - off]; }
        __syncthreads();
        if (t < 128) sc[t] = xv + y;
        __syncthreads();
    }
    if (t < NBK) {
        lo[t] = sc[t] - cnt[t];
        gb[t] = cnt[t] ? atomicAdd(&gcur[t], cnt[t]) : 0;
    }
    __syncthreads();
    if (val) {
        #pragma unroll
        for (int k = 0; k < 4; ++k) {
            int pos = lo[bk[k]] + rk[k];
            sS[pos] = (&s4.x)[k];
            dS[pos] = (&d4.x)[k];
            gS[pos] = gb[bk[k]] + rk[k];
        }
    }
    __syncthreads();
    int tot = N_EDGES - blockIdx.x * PART_EPB;
    if (tot > PART_EPB) tot = PART_EPB;
    for (int i = t; i < tot; i += 256)
        rec[gS[i]] = make_int2(sS[i], dS[i]);
}

// Phase 2a: per-bucket deg histogram (dense 4KB window per bucket, XCD-pinned).
__global__ __launch_bounds__(256) void k_dhist(const int2* __restrict__ rec,
                                               const int* __restrict__ bbase,
                                               const int* __restrict__ bcnt,
                                               int* __restrict__ deg) {
    int r = blockIdx.x & 7, q = blockIdx.x >> 3;
    int b = (q / BCH) * 8 + r, c = q % BCH;
    if (b >= NBK) return;
    int n = bcnt[b];
    int hi = (c + 1) * 4096; if (hi > n) hi = n;
    const int2* rp = rec + bbase[b];
    for (int i = c * 4096 + threadIdx.x; i < hi; i += 256)
        atomicAdd(&deg[rp[i].y], 1);
}

__global__ __launch_bounds__(256) void k_scan_a(const int* __restrict__ deg,
                                                int* __restrict__ S,
                                                int* __restrict__ blockSum) {
    __shared__ int lds[256];
    int t = threadIdx.x;
    int base = blockIdx.x * 1024 + t * 4;
    int v[4]; int sum = 0;
    #pragma unroll
    for (int k = 0; k < 4; ++k) { int i = base + k; v[k] = (i < N_NODES) ? deg[i] : 0; sum += v[k]; }
    lds[t] = sum; __syncthreads();
    for (int off = 1; off < 256; off <<= 1) {
        int x = lds[t];
        int y = (t >= off) ? lds[t - off] : 0;
        __syncthreads();
        lds[t] = x + y;
        __syncthreads();
    }
    int run = lds[t] - sum;
    #pragma unroll
    for (int k = 0; k < 4; ++k) {
        run += v[k];
        int i = base + k;
        if (i < N_NODES) S[i] = run;
    }
    if (t == 255) blockSum[blockIdx.x] = lds[255];
}

__global__ __launch_bounds__(256) void k_scan_b(const int* __restrict__ blockSum,
                                                int* __restrict__ blockOff) {
    __shared__ int lds[256];
    int t = threadIdx.x;
    int v = (t < NB) ? blockSum[t] : 0;
    lds[t] = v; __syncthreads();
    for (int off = 1; off < 256; off <<= 1) {
        int x = lds[t];
        int y = (t >= off) ? lds[t - off] : 0;
        __syncthreads();
        lds[t] = x + y;
        __syncthreads();
    }
    if (t < NB) blockOff[t] = lds[t] - v;
}

__global__ __launch_bounds__(256) void k_scan_c(int* __restrict__ S,
                                                const int* __restrict__ deg,
                                                const int* __restrict__ blockOff,
                                                int* __restrict__ cursor) {
    int i = blockIdx.x * 256 + threadIdx.x;
    if (i < N_NODES) {
        int s = S[i] + blockOff[i >> 10];
        S[i] = s;
        cursor[i] = s - deg[i];
    }
}

// Phase 2b: final scatter within bucket windows (~64KB ssrc + 4KB cursor,
// L2-resident & temporally dense, same-XCD blocks).
__global__ __launch_bounds__(256) void k_scat2(const int2* __restrict__ rec,
                                               const int* __restrict__ bbase,
                                               const int* __restrict__ bcnt,
                                               int* __restrict__ cursor,
                                               int* __restrict__ ssrc) {
    int r = blockIdx.x & 7, q = blockIdx.x >> 3;
    int b = (q / BCH) * 8 + r, c = q % BCH;
    if (b >= NBK) return;
    int n = bcnt[b];
    int hi = (c + 1) * 4096; if (hi > n) hi = n;
    const int2* rp = rec + bbase[b];
    for (int i = c * 4096 + threadIdx.x; i < hi; i += 256) {
        int2 e = rp[i];
        int pos = atomicAdd(&cursor[e.y], 1);
        ssrc[pos] = e.x;
    }
}

// ---------------- layer-1 aggregate + elu + @W2 + alpha2, fused ----------------
__global__ __launch_bounds__(256) void k_agg1(const int* __restrict__ ssrc,
                                              const int* __restrict__ S,
                                              const int* __restrict__ deg,
                                              const unsigned short* __restrict__ h1b,
                                              const float* __restrict__ as1,
                                              const float* __restrict__ ad1,
                                              const float* __restrict__ b1,
                                              const float* __restrict__ W2,
                                              const float* __restrict__ a_src2,
                                              const float* __restrict__ a_dst2,
                                              float4* __restrict__ pk2) {
    int node = blockIdx.x * 4 + (threadIdx.x >> 6);
    int lane = threadIdx.x & 63;
    if (node >= N_NODES) return;
    int h  = lane >> 3;
    int hw = lane & 7;
    int el = lane >> 3;
    int end = S[node], start = end - deg[node];

    float adh  = ad1[node * 8 + h];
    float adhw = ad1[node * 8 + hw];

    float ev = as1[node * 8 + h] + adh;
    ev = fmaxf(ev, NEG * ev);
    float wself = __expf(ev);
    float acc = wself * bf2f(h1b[node * 64 + lane]);
    float zw = 0.f;

    for (int c = start; c < end; c += 64) {
        int cnt = end - c; if (cnt > 64) cnt = 64;
        int sidx = (lane < cnt) ? ssrc[c + lane] : 0;
        int ng = (cnt + 7) >> 3;
        for (int g = 0; g < ng; ++g) {
            int eidx = g * 8 + el;
            int se = __shfl(sidx, eidx);
            float a = as1[se * 8 + hw];
            float e0 = a + adhw;
            e0 = fmaxf(e0, NEG * e0);
            float wv = (eidx < cnt) ? __expf(e0) : 0.f;
            zw += wv;
            #pragma unroll
            for (int e = 0; e < 8; ++e) {
                int sb = __builtin_amdgcn_readlane(sidx, g * 8 + e);
                float wb = __shfl(wv, e * 8 + el);
                float gm = bf2f(h1b[sb * 64 + lane]);
                acc = fmaf(wb, gm, acc);
            }
        }
    }

    zw += __shfl_xor(zw, 8); zw += __shfl_xor(zw, 16); zw += __shfl_xor(zw, 32);
    float z = __shfl(zw, h) + wself;

    float o = acc / z + b1[lane];
    o = o > 0.f ? o : expm1f(o);
    float p0 = o * W2[lane * 2 + 0];
    float p1 = o * W2[lane * 2 + 1];
    #pragma unroll
    for (int m = 1; m < 64; m <<= 1) { p0 += __shfl_xor(p0, m); p1 += __shfl_xor(p1, m); }
    if (lane == 0) {
        pk2[node] = make_float4(p0, p1,
                                p0 * a_src2[0] + p1 * a_src2[1],
                                p0 * a_dst2[0] + p1 * a_dst2[1]);
    }
}

// ---------------- layer-2 aggregate + log_softmax, fused ----------------
__global__ __launch_bounds__(256) void k_agg2(const int* __restrict__ ssrc,
                                              const int* __restrict__ S,
                                              const int* __restrict__ deg,
                                              const float4* __restrict__ pk2,
                                              const float* __restrict__ b2,
                                              float* __restrict__ out) {
    int node = blockIdx.x * 16 + (threadIdx.x >> 4);
    int j = threadIdx.x & 15;
    if (node >= N_NODES) return;
    int end = S[node], start = end - deg[node];
    float4 self = pk2[node];
    float ad = self.w;
    float acc0 = 0.f, acc1 = 0.f, z = 0.f;
    if (j == 0) {
        float ev = self.z + ad;
        ev = fmaxf(ev, NEG * ev);
        float w = __expf(ev);
        acc0 = w * self.x; acc1 = w * self.y; z = w;
    }
    int i = start + j;
    for (; i + 16 < end; i += 32) {
        int s0 = ssrc[i], s1 = ssrc[i + 16];
        float4 q0 = pk2[s0], q1 = pk2[s1];
        float e0 = q0.z + ad; e0 = fmaxf(e0, NEG * e0); float w0 = __expf(e0);
        float e1 = q1.z + ad; e1 = fmaxf(e1, NEG * e1); float w1 = __expf(e1);
        acc0 = fmaf(w0, q0.x, acc0); acc0 = fmaf(w1, q1.x, acc0);
        acc1 = fmaf(w0, q0.y, acc1); acc1 = fmaf(w1, q1.y, acc1);
        z += w0 + w1;
    }
    if (i < end) {
        int s = ssrc[i];
        float4 q = pk2[s];
        float e0 = q.z + ad; e0 = fmaxf(e0, NEG * e0); float w0 = __expf(e0);
        acc0 = fmaf(w0, q.x, acc0);
        acc1 = fmaf(w0, q.y, acc1);
        z += w0;
    }
    #pragma unroll
    for (int m = 1; m < 16; m <<= 1) {
        acc0 += __shfl_xor(acc0, m);
        acc1 += __shfl_xor(acc1, m);
        z    += __shfl_xor(z, m);
    }
    if (j == 0) {
        float v0 = acc0 / z + b2[0];
        float v1 = acc1 / z + b2[1];
        float m = fmaxf(v0, v1);
        float lse = m + logf(__expf(v0 - m) + __expf(v1 - m));
        out[node * 2 + 0] = v0 - lse;
        out[node * 2 + 1] = v1 - lse;
    }
}

extern "C" void kernel_launch(void* const* d_in, const int* in_sizes, int n_in,
                              void* d_out, int out_size, void* d_ws, size_t ws_size,
                              hipStream_t stream) {
    const float* x      = (const float*)d_in[0];
    const int*   ei     = (const int*)d_in[1];
    const float* W1     = (const float*)d_in[2];
    const float* a_src1 = (const float*)d_in[3];
    const float* a_dst1 = (const float*)d_in[4];
    const float* b1     = (const float*)d_in[5];
    const float* W2     = (const float*)d_in[6];
    const float* a_src2 = (const float*)d_in[7];
    const float* a_dst2 = (const float*)d_in[8];
    const float* b2     = (const float*)d_in[9];
    float* out = (float*)d_out;

    float* p = (float*)d_ws;
    unsigned short* h1b = (unsigned short*)p; p += N_NODES * 32;  // bf16 [N][64]
    float* as1  = p; p += N_NODES * 8;
    float* ad1  = p; p += N_NODES * 8;
    float4* pk2 = (float4*)p; p += N_NODES * 4;
    int* ip = (int*)p;
    int* deg      = ip; ip += N_NODES;   // deg, bcnt, gcur contiguous: one memset
    int* bcnt     = ip; ip += 128;
    int* gcur     = ip; ip += 128;
    int* bbase    = ip; ip += 128;
    int* S        = ip; ip += N_NODES;
    int* cursor   = ip; ip += N_NODES;
    int* blockSum = ip; ip += 256;
    int* blockOff = ip; ip += 256;
    int* ssrc     = ip; ip += N_EDGES;
    int2* rec     = (int2*)ip; ip += 2 * N_EDGES;
    unsigned short* Wth = (unsigned short*)ip;
    unsigned short* Wtl = Wth + 64 * KPAD;

    hipMemsetAsync(deg, 0, (N_NODES + 256) * sizeof(int), stream);  // deg+bcnt+gcur

    // CSR build: two-phase multisplit
    k_bhist<<<(N_EDGES + 4095) / 4096, 256, 0, stream>>>(ei, bcnt);
    k_bscan<<<1, 128, 0, stream>>>(bcnt, bbase, gcur);
    k_part<<<NPART, 256, 0, stream>>>(ei, gcur, rec);
    k_dhist<<<DH_GRID, 256, 0, stream>>>(rec, bbase, bcnt, deg);
    k_scan_a<<<NB, 256, 0, stream>>>(deg, S, blockSum);
    k_scan_b<<<1, 256, 0, stream>>>(blockSum, blockOff);
    k_scan_c<<<(N_NODES + 255) / 256, 256, 0, stream>>>(S, deg, blockOff, cursor);
    k_scat2<<<DH_GRID, 256, 0, stream>>>(rec, bbase, bcnt, cursor, ssrc);

    // layer 1: register-direct MFMA GEMM, x converted in-register
    k_wconv<<<(64 * KPAD + 255) / 256, 256, 0, stream>>>(W1, Wth, Wtl);
    k_gemm1<<<(N_NODES / 16 + 3) / 4, 256, 0, stream>>>(x, Wth, Wtl,
                                                        a_src1, a_dst1, h1b, as1, ad1);
    k_agg1<<<(N_NODES + 3) / 4, 256, 0, stream>>>(ssrc, S, deg, h1b, as1, ad1, b1, W2,
                                                  a_src2, a_dst2, pk2);
    // layer 2 + log_softmax
    k_agg2<<<(N_NODES + 15) / 16, 256, 0, stream>>>(ssrc, S, deg, pk2, b2, out);
}

// Round 10
// 196.380 us; speedup vs baseline: 1.7045x; 1.4376x over previous
//
#include <hip/hip_runtime.h>
#include <math.h>

#define N_NODES 100000
#define N_EDGES 1600000
#define F_IN 165
#define KPAD 192
#define NEG 0.2f
#define BK_SHIFT 10
#define BKSZ 1024
#define NBK 98           // ceil(N_NODES / 1024) dst buckets
#define PART_EPB 4096    // edges per k_part block (256 thr x 16)
#define NPART ((N_EDGES + PART_EPB - 1) / PART_EPB)
#define RECCAP 17408     // LDS-staged records per bucket (mean 16327, sd ~128)

typedef __attribute__((ext_vector_type(8))) short short8v;
typedef __attribute__((ext_vector_type(4))) float f32x4;

static __device__ __forceinline__ unsigned short f2bf(float f) {
    unsigned int u = __float_as_uint(f);
    unsigned int r = (u + 0x7FFFu + ((u >> 16) & 1u)) >> 16;
    return (unsigned short)r;
}
static __device__ __forceinline__ float bf2f(unsigned short b) {
    return __uint_as_float((unsigned int)b << 16);
}

// ---------------- W1 -> transposed bf16 hi/lo [64 cols][192 k] ----------------
__global__ __launch_bounds__(256) void k_wconv(const float* __restrict__ W1,
                                               unsigned short* __restrict__ Wth,
                                               unsigned short* __restrict__ Wtl) {
    int i = blockIdx.x * 256 + threadIdx.x;
    if (i >= 64 * KPAD) return;
    int col = i / KPAD, k = i % KPAD;
    float f = (k < F_IN) ? W1[k * 64 + col] : 0.f;
    unsigned short hi = f2bf(f);
    Wth[i] = hi;
    Wtl[i] = f2bf(f - bf2f(hi));
}

// ---------------- K1: h1 = x @ W1 via bf16 MFMA, register-direct, no LDS ----------------
__global__ __launch_bounds__(256) void k_gemm1(const float* __restrict__ x,
                                               const unsigned short* __restrict__ Wth,
                                               const unsigned short* __restrict__ Wtl,
                                               const float* __restrict__ a_src1,
                                               const float* __restrict__ a_dst1,
                                               unsigned short* __restrict__ h1b,
                                               float* __restrict__ as1,
                                               float* __restrict__ ad1) {
    const int t = threadIdx.x;
    const int w = t >> 6, lane = t & 63;
    const int rowblk = blockIdx.x * 4 + w;
    if (rowblk * 16 >= N_NODES) return;
    const int lrow = lane & 15, lk = lane >> 4;
    const int arow = rowblk * 16 + lrow;

    const float* xp = x + (size_t)arow * F_IN + lk * 8;
    const int klo = lk * 8;

    f32x4 acc[4] = {};
    #pragma unroll
    for (int c = 0; c < 6; ++c) {
        float f[8];
        #pragma unroll
        for (int j = 0; j < 8; ++j) {
            int k = c * 32 + klo + j;
            f[j] = (c < 5 || k < F_IN) ? xp[c * 32 + j] : 0.f;
        }
        unsigned int uh[8], ul[8];
        #pragma unroll
        for (int j = 0; j < 8; ++j) {
            unsigned int u = __float_as_uint(f[j]);
            uh[j] = u;
            float lo = f[j] - __uint_as_float(u & 0xFFFF0000u);
            ul[j] = __float_as_uint(lo);
        }
        union { int4 d; short8v s; } ah, al;
        ah.d.x = __builtin_amdgcn_perm(uh[1], uh[0], 0x07060302u);
        ah.d.y = __builtin_amdgcn_perm(uh[3], uh[2], 0x07060302u);
        ah.d.z = __builtin_amdgcn_perm(uh[5], uh[4], 0x07060302u);
        ah.d.w = __builtin_amdgcn_perm(uh[7], uh[6], 0x07060302u);
        al.d.x = __builtin_amdgcn_perm(ul[1], ul[0], 0x07060302u);
        al.d.y = __builtin_amdgcn_perm(ul[3], ul[2], 0x07060302u);
        al.d.z = __builtin_amdgcn_perm(ul[5], ul[4], 0x07060302u);
        al.d.w = __builtin_amdgcn_perm(ul[7], ul[6], 0x07060302u);
        #pragma unroll
        for (int ct = 0; ct < 4; ++ct) {
            const short8v b_h = *(const short8v*)(Wth + (ct * 16 + lrow) * KPAD + c * 32 + klo);
            const short8v b_l = *(const short8v*)(Wtl + (ct * 16 + lrow) * KPAD + c * 32 + klo);
            acc[ct] = __builtin_amdgcn_mfma_f32_16x16x32_bf16(ah.s, b_h, acc[ct], 0, 0, 0);
            acc[ct] = __builtin_amdgcn_mfma_f32_16x16x32_bf16(ah.s, b_l, acc[ct], 0, 0, 0);
            acc[ct] = __builtin_amdgcn_mfma_f32_16x16x32_bf16(al.s, b_h, acc[ct], 0, 0, 0);
        }
    }

    #pragma unroll
    for (int ct = 0; ct < 4; ++ct) {
        int colbase = ct * 16 + lrow;
        float av = a_src1[colbase], dv = a_dst1[colbase];
        #pragma unroll
        for (int r = 0; r < 4; ++r) {
            int row = rowblk * 16 + lk * 4 + r;
            float v = acc[ct][r];
            h1b[row * 64 + colbase] = f2bf(v);
            float ps = v * av, pd = v * dv;
            ps += __shfl_xor(ps, 1); ps += __shfl_xor(ps, 2); ps += __shfl_xor(ps, 4);
            pd += __shfl_xor(pd, 1); pd += __shfl_xor(pd, 2); pd += __shfl_xor(pd, 4);
            if ((lane & 7) == 0) {
                int head = ct * 2 + (lrow >> 3);
                as1[row * 8 + head] = ps;
                ad1[row * 8 + head] = pd;
            }
        }
    }
}

// ---------------- CSR build: multisplit + per-bucket LDS finalize ----------------
// Phase 0: bucket histogram (bucket = dst >> 10).
__global__ __launch_bounds__(256) void k_bhist(const int* __restrict__ ei,
                                               int* __restrict__ bcnt) {
    __shared__ int cnt[NBK];
    int t = threadIdx.x;
    for (int i = t; i < NBK; i += 256) cnt[i] = 0;
    __syncthreads();
    long base = (long)blockIdx.x * 4096 + t * 4;
    #pragma unroll
    for (int q = 0; q < 4; ++q) {
        long e0 = base + q * 1024;
        if (e0 < N_EDGES) {
            int4 d4 = *(const int4*)(ei + N_EDGES + e0);
            atomicAdd(&cnt[d4.x >> BK_SHIFT], 1);
            atomicAdd(&cnt[d4.y >> BK_SHIFT], 1);
            atomicAdd(&cnt[d4.z >> BK_SHIFT], 1);
            atomicAdd(&cnt[d4.w >> BK_SHIFT], 1);
        }
    }
    __syncthreads();
    for (int i = t; i < NBK; i += 256) if (cnt[i]) atomicAdd(&bcnt[i], cnt[i]);
}

__global__ __launch_bounds__(128) void k_bscan(const int* __restrict__ bcnt,
                                               int* __restrict__ bbase,
                                               int* __restrict__ gcur) {
    __shared__ int lds[128];
    int t = threadIdx.x;
    int v = (t < NBK) ? bcnt[t] : 0;
    lds[t] = v; __syncthreads();
    for (int off = 1; off < 128; off <<= 1) {
        int x = lds[t];
        int y = (t >= off) ? lds[t - off] : 0;
        __syncthreads();
        lds[t] = x + y;
        __syncthreads();
    }
    if (t < NBK) { int ex = lds[t] - v; bbase[t] = ex; gcur[t] = ex; }
}

// Phase 1: partition packed records (s<<10 | dlow) into bucket regions;
// block-local LDS rank+sort so global writes are ~42-int contiguous runs.
__global__ __launch_bounds__(256) void k_part(const int* __restrict__ ei,
                                              int* __restrict__ gcur,
                                              int* __restrict__ rec) {
    __shared__ int cnt[NBK], lo[NBK], gb[NBK];
    __shared__ int sc[128];
    __shared__ int stR[PART_EPB], stG[PART_EPB];
    int t = threadIdx.x;
    for (int i = t; i < NBK; i += 256) cnt[i] = 0;
    __syncthreads();
    long base = (long)blockIdx.x * PART_EPB + t * 4;
    int4 s4[4], d4[4];
    int bk[16], rk[16];
    bool val[4];
    #pragma unroll
    for (int q = 0; q < 4; ++q) {
        long e0 = base + q * 1024;
        val[q] = e0 < N_EDGES;
        if (val[q]) {
            s4[q] = *(const int4*)(ei + e0);
            d4[q] = *(const int4*)(ei + N_EDGES + e0);
            #pragma unroll
            for (int k = 0; k < 4; ++k) {
                int d = (&d4[q].x)[k];
                bk[q * 4 + k] = d >> BK_SHIFT;
                rk[q * 4 + k] = atomicAdd(&cnt[d >> BK_SHIFT], 1);
            }
        }
    }
    __syncthreads();
    if (t < 128) sc[t] = (t < NBK) ? cnt[t] : 0;
    __syncthreads();
    for (int off = 1; off < 128; off <<= 1) {
        int xv = 0, y = 0;
        if (t < 128) { xv = sc[t]; if (t >= off) y = sc[t - off]; }
        __syncthreads();
        if (t < 128) sc[t] = xv + y;
        __syncthreads();
    }
    if (t < NBK) {
        lo[t] = sc[t] - cnt[t];
        gb[t] = cnt[t] ? atomicAdd(&gcur[t], cnt[t]) : 0;
    }
    __syncthreads();
    #pragma unroll
    for (int q = 0; q < 4; ++q) {
        if (val[q]) {
            #pragma unroll
            for (int k = 0; k < 4; ++k) {
                int b = bk[q * 4 + k], r = rk[q * 4 + k];
                int pos = lo[b] + r;
                stR[pos] = ((&s4[q].x)[k] << BK_SHIFT) | ((&d4[q].x)[k] & (BKSZ - 1));
                stG[pos] = gb[b] + r;
            }
        }
    }
    __syncthreads();
    long rem = N_EDGES - (long)blockIdx.x * PART_EPB;
    int tot = rem > PART_EPB ? PART_EPB : (int)rem;
    for (int i = t; i < tot; i += 256)
        rec[stG[i]] = stR[i];
}

// Phase 2 (fused): per bucket — stage records in LDS, histogram deg, scan,
// write S/deg, scatter ssrc via LDS cursors. No global atomics, no extra scans.
__global__ __launch_bounds__(256) void k_bfin(const int* __restrict__ rec,
                                              const int* __restrict__ bbase,
                                              const int* __restrict__ bcnt,
                                              int* __restrict__ S,
                                              int* __restrict__ deg,
                                              int* __restrict__ ssrc) {
    __shared__ int lrec[RECCAP];
    __shared__ int ldeg[BKSZ];
    __shared__ int lsum[256];
    int b = blockIdx.x, t = threadIdx.x;
    int n = bcnt[b], base = bbase[b];
    for (int i = t; i < BKSZ; i += 256) ldeg[i] = 0;
    __syncthreads();
    for (int i = t; i < n; i += 256) {
        int r = rec[base + i];
        if (i < RECCAP) lrec[i] = r;
        atomicAdd(&ldeg[r & (BKSZ - 1)], 1);
    }
    __syncthreads();
    int v0 = ldeg[t * 4], v1 = ldeg[t * 4 + 1], v2 = ldeg[t * 4 + 2], v3 = ldeg[t * 4 + 3];
    int s = v0 + v1 + v2 + v3;
    lsum[t] = s;
    __syncthreads();
    for (int off = 1; off < 256; off <<= 1) {
        int x = lsum[t];
        int y = (t >= off) ? lsum[t - off] : 0;
        __syncthreads();
        lsum[t] = x + y;
        __syncthreads();
    }
    int ex = lsum[t] - s;
    // global S (edge prefix) + deg; LDS cursors (exclusive starts)
    int nodeb = b * BKSZ + t * 4;
    int i0 = ex, i1 = ex + v0, i2 = i1 + v1, i3 = i2 + v2;
    if (nodeb     < N_NODES) { S[nodeb]     = base + i1;      deg[nodeb]     = v0; }
    if (nodeb + 1 < N_NODES) { S[nodeb + 1] = base + i2;      deg[nodeb + 1] = v1; }
    if (nodeb + 2 < N_NODES) { S[nodeb + 2] = base + i3;      deg[nodeb + 2] = v2; }
    if (nodeb + 3 < N_NODES) { S[nodeb + 3] = base + i3 + v3; deg[nodeb + 3] = v3; }
    ldeg[t * 4]     = i0;
    ldeg[t * 4 + 1] = i1;
    ldeg[t * 4 + 2] = i2;
    ldeg[t * 4 + 3] = i3;
    __syncthreads();
    for (int i = t; i < n; i += 256) {
        int r = (i < RECCAP) ? lrec[i] : rec[base + i];
        int pos = atomicAdd(&ldeg[r & (BKSZ - 1)], 1);
        ssrc[base + pos] = r >> BK_SHIFT;
    }
}

// ---------------- layer-1 aggregate + elu + @W2 + alpha2, fused ----------------
__global__ __launch_bounds__(256) void k_agg1(const int* __restrict__ ssrc,
                                              const int* __restrict__ S,
                                              const int* __restrict__ deg,
                                              const unsigned short* __restrict__ h1b,
                                              const float* __restrict__ as1,
                                              const float* __restrict__ ad1,
                                              const float* __restrict__ b1,
                                              const float* __restrict__ W2,
                                              const float* __restrict__ a_src2,
                                              const float* __restrict__ a_dst2,
                                              float4* __restrict__ pk2) {
    int node = blockIdx.x * 4 + (threadIdx.x >> 6);
    int lane = threadIdx.x & 63;
    if (node >= N_NODES) return;
    int h  = lane >> 3;
    int hw = lane & 7;
    int el = lane >> 3;
    int end = S[node], start = end - deg[node];

    float adh  = ad1[node * 8 + h];
    float adhw = ad1[node * 8 + hw];

    float ev = as1[node * 8 + h] + adh;
    ev = fmaxf(ev, NEG * ev);
    float wself = __expf(ev);
    float acc = wself * bf2f(h1b[node * 64 + lane]);
    float zw = 0.f;

    for (int c = start; c < end; c += 64) {
        int cnt = end - c; if (cnt > 64) cnt = 64;
        int sidx = (lane < cnt) ? ssrc[c + lane] : 0;
        int ng = (cnt + 7) >> 3;
        for (int g = 0; g < ng; ++g) {
            int eidx = g * 8 + el;
            int se = __shfl(sidx, eidx);
            float a = as1[se * 8 + hw];
            float e0 = a + adhw;
            e0 = fmaxf(e0, NEG * e0);
            float wv = (eidx < cnt) ? __expf(e0) : 0.f;
            zw += wv;
            #pragma unroll
            for (int e = 0; e < 8; ++e) {
                int sb = __builtin_amdgcn_readlane(sidx, g * 8 + e);
                float wb = __shfl(wv, e * 8 + el);
                float gm = bf2f(h1b[sb * 64 + lane]);
                acc = fmaf(wb, gm, acc);
            }
        }
    }

    zw += __shfl_xor(zw, 8); zw += __shfl_xor(zw, 16); zw += __shfl_xor(zw, 32);
    float z = __shfl(zw, h) + wself;

    float o = acc / z + b1[lane];
    o = o > 0.f ? o : expm1f(o);
    float p0 = o * W2[lane * 2 + 0];
    float p1 = o * W2[lane * 2 + 1];
    #pragma unroll
    for (int m = 1; m < 64; m <<= 1) { p0 += __shfl_xor(p0, m); p1 += __shfl_xor(p1, m); }
    if (lane == 0) {
        pk2[node] = make_float4(p0, p1,
                                p0 * a_src2[0] + p1 * a_src2[1],
                                p0 * a_dst2[0] + p1 * a_dst2[1]);
    }
}

// ---------------- layer-2 aggregate + log_softmax, fused ----------------
__global__ __launch_bounds__(256) void k_agg2(const int* __restrict__ ssrc,
                                              const int* __restrict__ S,
                                              const int* __restrict__ deg,
                                              const float4* __restrict__ pk2,
                                              const float* __restrict__ b2,
                                              float* __restrict__ out) {
    int node = blockIdx.x * 16 + (threadIdx.x >> 4);
    int j = threadIdx.x & 15;
    if (node >= N_NODES) return;
    int end = S[node], start = end - deg[node];
    float4 self = pk2[node];
    float ad = self.w;
    float acc0 = 0.f, acc1 = 0.f, z = 0.f;
    if (j == 0) {
        float ev = self.z + ad;
        ev = fmaxf(ev, NEG * ev);
        float w = __expf(ev);
        acc0 = w * self.x; acc1 = w * self.y; z = w;
    }
    int i = start + j;
    for (; i + 16 < end; i += 32) {
        int s0 = ssrc[i], s1 = ssrc[i + 16];
        float4 q0 = pk2[s0], q1 = pk2[s1];
        float e0 = q0.z + ad; e0 = fmaxf(e0, NEG * e0); float w0 = __expf(e0);
        float e1 = q1.z + ad; e1 = fmaxf(e1, NEG * e1); float w1 = __expf(e1);
        acc0 = fmaf(w0, q0.x, acc0); acc0 = fmaf(w1, q1.x, acc0);
        acc1 = fmaf(w0, q0.y, acc1); acc1 = fmaf(w1, q1.y, acc1);
        z += w0 + w1;
    }
    if (i < end) {
        int s = ssrc[i];
        float4 q = pk2[s];
        float e0 = q.z + ad; e0 = fmaxf(e0, NEG * e0); float w0 = __expf(e0);
        acc0 = fmaf(w0, q.x, acc0);
        acc1 = fmaf(w0, q.y, acc1);
        z += w0;
    }
    #pragma unroll
    for (int m = 1; m < 16; m <<= 1) {
        acc0 += __shfl_xor(acc0, m);
        acc1 += __shfl_xor(acc1, m);
        z    += __shfl_xor(z, m);
    }
    if (j == 0) {
        float v0 = acc0 / z + b2[0];
        float v1 = acc1 / z + b2[1];
        float m = fmaxf(v0, v1);
        float lse = m + logf(__expf(v0 - m) + __expf(v1 - m));
        out[node * 2 + 0] = v0 - lse;
        out[node * 2 + 1] = v1 - lse;
    }
}

extern "C" void kernel_launch(void* const* d_in, const int* in_sizes, int n_in,
                              void* d_out, int out_size, void* d_ws, size_t ws_size,
                              hipStream_t stream) {
    const float* x      = (const float*)d_in[0];
    const int*   ei     = (const int*)d_in[1];
    const float* W1     = (const float*)d_in[2];
    const float* a_src1 = (const float*)d_in[3];
    const float* a_dst1 = (const float*)d_in[4];
    const float* b1     = (const float*)d_in[5];
    const float* W2     = (const float*)d_in[6];
    const float* a_src2 = (const float*)d_in[7];
    const float* a_dst2 = (const float*)d_in[8];
    const float* b2     = (const float*)d_in[9];
    float* out = (float*)d_out;

    float* p = (float*)d_ws;
    unsigned short* h1b = (unsigned short*)p; p += N_NODES * 32;  // bf16 [N][64]
    float* as1  = p; p += N_NODES * 8;
    float* ad1  = p; p += N_NODES * 8;
    float4* pk2 = (float4*)p; p += N_NODES * 4;
    int* ip = (int*)p;
    int* bcnt     = ip; ip += 128;      // bcnt+gcur contiguous: one memset
    int* gcur     = ip; ip += 128;
    int* bbase    = ip; ip += 128;
    int* deg      = ip; ip += N_NODES;
    int* S        = ip; ip += N_NODES;
    int* ssrc     = ip; ip += N_EDGES;
    int* rec      = ip; ip += N_EDGES;
    unsigned short* Wth = (unsigned short*)ip;
    unsigned short* Wtl = Wth + 64 * KPAD;

    hipMemsetAsync(bcnt, 0, 256 * sizeof(int), stream);   // bcnt + gcur

    // CSR build: bucket-hist -> scan -> partition (packed) -> per-bucket finalize
    k_bhist<<<(N_EDGES + 4095) / 4096, 256, 0, stream>>>(ei, bcnt);
    k_bscan<<<1, 128, 0, stream>>>(bcnt, bbase, gcur);
    k_part<<<NPART, 256, 0, stream>>>(ei, gcur, rec);
    k_bfin<<<NBK, 256, 0, stream>>>(rec, bbase, bcnt, S, deg, ssrc);

    // layer 1: register-direct MFMA GEMM, x converted in-register
    k_wconv<<<(64 * KPAD + 255) / 256, 256, 0, stream>>>(W1, Wth, Wtl);
    k_gemm1<<<(N_NODES / 16 + 3) / 4, 256, 0, stream>>>(x, Wth, Wtl,
                                                        a_src1, a_dst1, h1b, as1, ad1);
    k_agg1<<<(N_NODES + 3) / 4, 256, 0, stream>>>(ssrc, S, deg, h1b, as1, ad1, b1, W2,
                                                  a_src2, a_dst2, pk2);
    // layer 2 + log_softmax
    k_agg2<<<(N_NODES + 15) / 16, 256, 0, stream>>>(ssrc, S, deg, pk2, b2, out);
}